// Round 3
// baseline (287.173 us; speedup 1.0000x reference)
//
#include <hip/hip_runtime.h>
#include <stdint.h>

#define DEVFN __device__ __forceinline__

typedef short s16x8 __attribute__((ext_vector_type(8)));
typedef __bf16 bf16x8 __attribute__((ext_vector_type(8)));
typedef float fx4 __attribute__((ext_vector_type(4)));

// Problem constants (fixed by the reference)
constexpr int SEQ = 8192, DIM = 1280, HEADS = 16;
constexpr int NIMG = 32;
constexpr int NQKV = 3840;  // 3*DIM
constexpr int TS = 84;      // raw Q/K tile stride (168B rows: scatter = 2 lanes/bank, free)

DEVFN unsigned short f2bf(float f) {
  union { float f; unsigned u; } v; v.f = f;
  unsigned r = v.u + 0x7FFFu + ((v.u >> 16) & 1u);  // RNE
  return (unsigned short)(r >> 16);
}
DEVFN float bf2f(unsigned short u) {
  union { unsigned u; float f; } v; v.u = ((unsigned)u) << 16;
  return v.f;
}

DEVFN fx4 mfma16(s16x8 a, s16x8 b, fx4 c) {
  return __builtin_amdgcn_mfma_f32_16x16x32_bf16(
      __builtin_bit_cast(bf16x8, a), __builtin_bit_cast(bf16x8, b), c, 0, 0, 0);
}

DEVFN void gload_lds16(const void* g, void* l) {
  // global -> LDS direct, 16B per lane; LDS dest = wave-uniform base + lane*16
  __builtin_amdgcn_global_load_lds(
      (__attribute__((address_space(1))) void*)(uintptr_t)g,
      (__attribute__((address_space(3))) void*)l, 16, 0, 0);
}

// ---------------- f32 -> bf16 cast, 4 elems/thread ----------------
__global__ __launch_bounds__(256) void cast_bf16_kernel(const float* __restrict__ in,
                                                        unsigned short* __restrict__ out,
                                                        int n4) {
  int i = blockIdx.x * 256 + threadIdx.x;
  if (i >= n4) return;
  float4 v = ((const float4*)in)[i];
  ushort4 o;
  o.x = f2bf(v.x); o.y = f2bf(v.y); o.z = f2bf(v.z); o.w = f2bf(v.w);
  ((ushort4*)out)[i] = o;
}

// ---------------- transpose + cast: T[n][k] = W[k][n], bf16 out ----------------
__global__ __launch_bounds__(256) void transpose_cast_kernel(const float* __restrict__ W,
                                                             unsigned short* __restrict__ T,
                                                             int K, int N) {
  __shared__ float tile[32][33];
  const int tx = threadIdx.x & 31, ty = threadIdx.x >> 5;  // 32x8
  const int n0 = blockIdx.x * 32, k0 = blockIdx.y * 32;
#pragma unroll
  for (int i = 0; i < 4; i++) {
    int r = ty + i * 8;
    tile[r][tx] = W[(size_t)(k0 + r) * N + n0 + tx];
  }
  __syncthreads();
#pragma unroll
  for (int i = 0; i < 4; i++) {
    int r = ty + i * 8;
    T[(size_t)(n0 + r) * K + k0 + tx] = f2bf(tile[tx][r]);
  }
}

// ---------------- mega kernel: QKV GEMM + bias + RoPE + attention ----------------
// Block = (img n, head h), 512 threads = 8 waves (4x2). GEMM: 256x256x1280.
// NEW: BK=32 quad-buffer ring (4 x 16KB per matrix, same 128KB footprint), depth-3
// prefetch with counted s_waitcnt vmcnt(8) (never drains to 0 in steady state, T3/T4)
// + s_setprio around the MFMA cluster (T5). LDS tile rows are 64B; chunk position
// XOR-swizzled by (row>>1)&3 -> ~2-way bank aliasing on ds_read_b128 (free).
// Epilogue scatters acc+bias branchlessly (stride-select) into raw Q/K (stride 84)
// and V directly transposed into Vt[80][264]; then rope + QK^T + softmax + PV.
// LDS (153600 B): ring Abuf 4x16K @0, Bbuf 4x16K @65536 (dead after K-loop);
// X@0 (rawK84 -> Ks[256][104] -> P-scratch 8x16x264), Y@67584 (rawQ84),
// Vt@110592 (80x264, written in epilogue, read by PV).
__global__ __launch_bounds__(512, 2) void mega_attn(const unsigned short* __restrict__ hb,
                                                    const unsigned short* __restrict__ wqkvT,
                                                    const float* __restrict__ b_qkv,
                                                    const float* __restrict__ cosb,
                                                    const float* __restrict__ sinb,
                                                    unsigned short* __restrict__ Ob) {
  __shared__ __attribute__((aligned(16))) char smem[153600];
  unsigned short* X = (unsigned short*)smem;
  unsigned short* Y = (unsigned short*)(smem + 67584);
  unsigned short* Vt = (unsigned short*)(smem + 110592);  // [80][264]
  char* Abuf = smem;          // 4 x 16384
  char* Bbuf = smem + 65536;  // 4 x 16384

  const int t = threadIdx.x;
  const int lane = t & 63, w = t >> 6;
  const int lrow = lane & 15, lq = lane >> 4;
  const int n = blockIdx.x, h = blockIdx.y;
  const int s0 = n * 256;
  const int wm = w >> 1, wn = w & 1;

  // staging geometry (BK=32): per matrix 1024 16B-chunks/step (256 rows x 4 chunks);
  // thread covers slots t and t+512. slot s -> row r = s>>2, pos p = s&3; stored pos p
  // holds global chunk p ^ ((r>>1)&3)  (swizzle -> ~2-way banks on ds_read_b128).
  // (r>>1)&3 reduces to (t>>3)&3 for both i (row offset 128 = 0 mod 8).
  const int tr2 = t >> 2;  // 0..127
  const int g8 = ((t & 3) ^ ((t >> 3) & 3)) * 8;
  const unsigned short* pA32[2];
  pA32[0] = hb + (size_t)(s0 + tr2) * 1280 + g8;
  pA32[1] = pA32[0] + (size_t)128 * 1280;
  const unsigned short* pB32[2];
#pragma unroll
  for (int i = 0; i < 2; i++) {
    const int r = tr2 + i * 128;
    const int rr = r < 240 ? r : 239;  // pad rows clamp (cols 240..255 never used)
    const int sgm = (rr >= 160) ? 2 : (rr >= 80 ? 1 : 0);
    pB32[i] = wqkvT + (size_t)(sgm * DIM + h * 80 + (rr - sgm * 80)) * 1280 + g8;
  }

  // fragment read offsets: row ra, chunk lq ^ ((ra>>1)&3); (ra>>1)&3 == (lrow>>1)&3.
  const int swzr = (lq ^ ((lrow >> 1) & 3)) * 16;
  int offA32[4], offB32[8];
#pragma unroll
  for (int i = 0; i < 4; i++) offA32[i] = (wm * 64 + i * 16 + lrow) * 64 + swzr;
#pragma unroll
  for (int j = 0; j < 8; j++) offB32[j] = (wn * 128 + j * 16 + lrow) * 64 + swzr;

  fx4 acc[4][8] = {};

  auto STAGE = [&](int k) {
    const int kof = k * 32;
    char* da = Abuf + (k & 3) * 16384 + w * 1024;
    char* db = Bbuf + (k & 3) * 16384 + w * 1024;
    gload_lds16(pA32[0] + kof, da);
    gload_lds16(pB32[0] + kof, db);
    gload_lds16(pA32[1] + kof, da + 8192);
    gload_lds16(pB32[1] + kof, db + 8192);
  };
  auto COMP = [&](int k) {
    const char* As = Abuf + (k & 3) * 16384;
    const char* Bs = Bbuf + (k & 3) * 16384;
    s16x8 a[4], b[8];
#pragma unroll
    for (int i = 0; i < 4; i++) a[i] = *(const s16x8*)(As + offA32[i]);
#pragma unroll
    for (int j = 0; j < 8; j++) b[j] = *(const s16x8*)(Bs + offB32[j]);
    __builtin_amdgcn_s_setprio(1);
#pragma unroll
    for (int i = 0; i < 4; i++)
#pragma unroll
      for (int j = 0; j < 8; j++)
        acc[i][j] = mfma16(a[i], b[j], acc[i][j]);
    __builtin_amdgcn_s_setprio(0);
  };

  // prologue: 3 K-steps in flight (12 loads/thread)
  STAGE(0); STAGE(1); STAGE(2);
  // main loop: each wave waits only its own oldest 4 loads (buf k) -> after the
  // barrier every wave's buf[k] is complete; bufs k+1,k+2 stay in flight ACROSS
  // the barrier (counted vmcnt, T4). Issuing buf[k+3] overwrites buf[k-1], which
  // all waves finished reading before this barrier.
  for (int k = 0; k < 38; k++) {
    asm volatile("s_waitcnt vmcnt(8)\n\ts_barrier" ::: "memory");
    if (k < 37) STAGE(k + 3);
    COMP(k);
  }
  asm volatile("s_waitcnt vmcnt(4)\n\ts_barrier" ::: "memory");
  COMP(38);
  asm volatile("s_waitcnt vmcnt(0)\n\ts_barrier" ::: "memory");
  COMP(39);
  __syncthreads();  // all fragment reads done before staging regions become Q/K/Vt

  // ---- epilogue scatter (branchless stride-select): acc + bias ->
  //      sgm 0/1: raw Q (Y) / K (X), addr = row*84 + d
  //      sgm 2:   Vt transposed,      addr = d*264 + row
#pragma unroll
  for (int j = 0; j < 8; j++) {
    const int col = wn * 128 + j * 16 + lrow;
    if (col < 240) {
      const int sgm = (col >= 160) ? 2 : (col >= 80 ? 1 : 0);
      const int d = col - sgm * 80;
      const float bv = b_qkv[sgm * DIM + h * 80 + d];
      unsigned short* dst = (sgm == 0) ? Y : (sgm == 1) ? X : Vt;
      const int rs = (sgm == 2) ? 1 : TS;
      const int dd = (sgm == 2) ? 264 : 1;
      const int dbase = d * dd;
#pragma unroll
      for (int i = 0; i < 4; i++) {
        const int row = wm * 64 + i * 16 + lq * 4;
#pragma unroll
        for (int r = 0; r < 4; r++)
          dst[(row + r) * rs + dbase] = f2bf(acc[i][j][r] + bv);
      }
    }
  }
  __syncthreads();  // B1: raw Q/K + Vt complete

  // ---- K rope -> regs; Q rope -> A-fragments (wave w owns q-rows w*32..w*32+31) ----
  unsigned short kout[5][8];
  int kro[5], kco[5];
#pragma unroll
  for (int i = 0; i < 5; i++) {
    const int idx = t + i * 512;
    const unsigned r = (unsigned)idx / 10u, c = (unsigned)idx % 10u;
    kro[i] = r; kco[i] = c;
    s16x8 xv = *(const s16x8*)&X[r * TS + c * 8];
    const unsigned cp = (c < 5) ? c + 5 : c - 5;  // partner chunk (+-40 elems)
    s16x8 pv = *(const s16x8*)&X[r * TS + cp * 8];
    const float sgn = (c < 5) ? -1.f : 1.f;
    const float* cf = cosb + (size_t)(s0 + r) * 80 + c * 8;
    const float* sf = sinb + (size_t)(s0 + r) * 80 + c * 8;
#pragma unroll
    for (int j = 0; j < 8; j++)
      kout[i][j] = f2bf(bf2f((unsigned short)xv[j]) * cf[j] +
                        sgn * bf2f((unsigned short)pv[j]) * sf[j]);
  }

  s16x8 aq[2][3];
#pragma unroll
  for (int rt = 0; rt < 2; rt++) {
#pragma unroll
    for (int c = 0; c < 3; c++) {
      const int row = w * 32 + rt * 16 + lrow;
      const int d0 = c * 32 + lq * 8;
      s16x8 fr = {};
      if (d0 < 80) {
        s16x8 xv = *(const s16x8*)&Y[row * TS + d0];
        const int dp = (d0 < 40) ? d0 + 40 : d0 - 40;
        s16x8 pv = *(const s16x8*)&Y[row * TS + dp];
        const float sgn = (d0 < 40) ? -1.f : 1.f;
        const float* cf = cosb + (size_t)(s0 + row) * 80 + d0;
        const float* sf = sinb + (size_t)(s0 + row) * 80 + d0;
#pragma unroll
        for (int j = 0; j < 8; j++)
          fr[j] = (short)f2bf(bf2f((unsigned short)xv[j]) * cf[j] +
                              sgn * bf2f((unsigned short)pv[j]) * sf[j]);
      }
      aq[rt][c] = fr;
    }
  }
  __syncthreads();  // B2: rawK/rawQ reads done

  // ---- write rope'd K at stride 104 (2-way bank aliasing = free) + zero pad ----
#pragma unroll
  for (int i = 0; i < 5; i++)
    *(int4*)&X[kro[i] * 104 + kco[i] * 8] = *(const int4*)kout[i];
  {
    const int r = t >> 1, wh = t & 1;
    const int4 z = {0, 0, 0, 0};
    *(int4*)&X[r * 104 + 80 + wh * 8] = z;
  }
  __syncthreads();  // B3

  // ---- QK^T: 2 row-tiles x 16 col-tiles, K = 96 ----
  fx4 acc2[2][16] = {};
#pragma unroll
  for (int c = 0; c < 3; c++) {
#pragma unroll
    for (int ct = 0; ct < 16; ct++) {
      s16x8 b = *(const s16x8*)&X[(ct * 16 + lrow) * 104 + c * 32 + lq * 8];
      acc2[0][ct] = mfma16(aq[0][c], b, acc2[0][ct]);
      acc2[1][ct] = mfma16(aq[1][c], b, acc2[1][ct]);
    }
  }

  // ---- softmax (rows wave-local: row = rt*16 + lq*4 + r) ----
  const float kscale = 0.11180339887498949f * 1.4426950408889634f;  // 80^-0.5 * log2e
  float inv[2][4];
#pragma unroll
  for (int rt = 0; rt < 2; rt++) {
    float mx[4] = {-1e30f, -1e30f, -1e30f, -1e30f};
#pragma unroll
    for (int ct = 0; ct < 16; ct++)
#pragma unroll
      for (int r = 0; r < 4; r++) mx[r] = fmaxf(mx[r], acc2[rt][ct][r]);
#pragma unroll
    for (int r = 0; r < 4; r++) {
      mx[r] = fmaxf(mx[r], __shfl_xor(mx[r], 1));
      mx[r] = fmaxf(mx[r], __shfl_xor(mx[r], 2));
      mx[r] = fmaxf(mx[r], __shfl_xor(mx[r], 4));
      mx[r] = fmaxf(mx[r], __shfl_xor(mx[r], 8));
    }
    float sm[4] = {0.f, 0.f, 0.f, 0.f};
#pragma unroll
    for (int ct = 0; ct < 16; ct++)
#pragma unroll
      for (int r = 0; r < 4; r++) {
        float e = exp2f((acc2[rt][ct][r] - mx[r]) * kscale);
        acc2[rt][ct][r] = e;
        sm[r] += e;
      }
#pragma unroll
    for (int r = 0; r < 4; r++) {
      sm[r] += __shfl_xor(sm[r], 1);
      sm[r] += __shfl_xor(sm[r], 2);
      sm[r] += __shfl_xor(sm[r], 4);
      sm[r] += __shfl_xor(sm[r], 8);
      inv[rt][r] = 1.f / sm[r];
    }
  }
  __syncthreads();  // B4: Ks dead; X becomes per-wave P-scratch

  // ---- P (rt=0) to per-wave scratch (wave-private: only lgkmcnt ordering needed,
  //      compiler inserts it; Vt has been complete since B1 -> no barrier here) ----
  unsigned short* Pw = X + w * 4224;  // 16 rows x 264 elems
#pragma unroll
  for (int ct = 0; ct < 16; ct++)
#pragma unroll
    for (int r = 0; r < 4; r++)
      Pw[(lq * 4 + r) * 264 + ct * 16 + lrow] = f2bf(acc2[0][ct][r] * inv[0][r]);

  // ---- PV + output, two 16-row sweeps ----
#pragma unroll
  for (int rt = 0; rt < 2; rt++) {
    if (rt == 1) {
#pragma unroll
      for (int ct = 0; ct < 16; ct++)
#pragma unroll
        for (int r = 0; r < 4; r++)
          Pw[(lq * 4 + r) * 264 + ct * 16 + lrow] = f2bf(acc2[1][ct][r] * inv[1][r]);
    }
    fx4 accO[5] = {};
#pragma unroll
    for (int kc = 0; kc < 8; kc++) {
      s16x8 a = *(const s16x8*)&Pw[lrow * 264 + kc * 32 + lq * 8];
#pragma unroll
      for (int tt = 0; tt < 5; tt++) {
        s16x8 b = *(const s16x8*)&Vt[(tt * 16 + lrow) * 264 + kc * 32 + lq * 8];
        accO[tt] = mfma16(a, b, accO[tt]);
      }
    }
    const int srow = s0 + w * 32 + rt * 16 + lq * 4;
#pragma unroll
    for (int tt = 0; tt < 5; tt++) {
      const int col = h * 80 + tt * 16 + lrow;
#pragma unroll
      for (int r = 0; r < 4; r++)
        Ob[(size_t)(srow + r) * DIM + col] = f2bf(accO[tt][r]);
    }
  }
}

// ---------------- proj GEMM: 128x128, BK=32 quad-buffer ring ----------------
// Same counted-vmcnt depth-3 pipeline as mega (T3/T4) + setprio (T5).
// LDS 64 KB (4 x 8K per matrix) -> 2 blocks/CU.
__global__ __launch_bounds__(256, 2) void gemm_proj(const unsigned short* __restrict__ A,
                                                    const unsigned short* __restrict__ Bt,
                                                    const float* __restrict__ bias,
                                                    float* __restrict__ C) {
  __shared__ __attribute__((aligned(16))) char smem[65536];
  char* Abuf = smem;           // 4 x 8192
  char* Bbuf = smem + 32768;   // 4 x 8192
  const int t = threadIdx.x;
  const int lane = t & 63, w = t >> 6;
  const int lrow = lane & 15, lq = lane >> 4;
  const int wm = w >> 1, wn = w & 1;  // 2x2 wave grid, 64x64 tiles
  const int m0 = blockIdx.x * 128, n0 = blockIdx.y * 128;

  // staging (BK=32): per matrix 512 chunks/step (128 rows x 4); thread covers
  // slots t and t+256. row = slot>>2, pos = slot&3 holds global chunk pos^((row>>1)&3).
  const int tr2 = t >> 2;  // 0..63
  const int g8 = ((t & 3) ^ ((t >> 3) & 3)) * 8;
  const unsigned short* pA32[2];
  pA32[0] = A + (size_t)(m0 + tr2) * 1280 + g8;
  pA32[1] = pA32[0] + (size_t)64 * 1280;
  const unsigned short* pB32[2];
  pB32[0] = Bt + (size_t)(n0 + tr2) * 1280 + g8;
  pB32[1] = pB32[0] + (size_t)64 * 1280;

  const int swzr = (lq ^ ((lrow >> 1) & 3)) * 16;
  int offA32[4], offB32[4];
#pragma unroll
  for (int i = 0; i < 4; i++) {
    offA32[i] = (wm * 64 + i * 16 + lrow) * 64 + swzr;
    offB32[i] = (wn * 64 + i * 16 + lrow) * 64 + swzr;
  }

  fx4 acc[4][4] = {};

  auto STAGE = [&](int k) {
    const int kof = k * 32;
    char* da = Abuf + (k & 3) * 8192 + w * 1024;
    char* db = Bbuf + (k & 3) * 8192 + w * 1024;
    gload_lds16(pA32[0] + kof, da);
    gload_lds16(pB32[0] + kof, db);
    gload_lds16(pA32[1] + kof, da + 4096);
    gload_lds16(pB32[1] + kof, db + 4096);
  };
  auto COMP = [&](int k) {
    const char* As = Abuf + (k & 3) * 8192;
    const char* Bs = Bbuf + (k & 3) * 8192;
    s16x8 a[4], b[4];
#pragma unroll
    for (int i = 0; i < 4; i++) a[i] = *(const s16x8*)(As + offA32[i]);
#pragma unroll
    for (int j = 0; j < 4; j++) b[j] = *(const s16x8*)(Bs + offB32[j]);
    __builtin_amdgcn_s_setprio(1);
#pragma unroll
    for (int i = 0; i < 4; i++)
#pragma unroll
      for (int j = 0; j < 4; j++)
        acc[i][j] = mfma16(a[i], b[j], acc[i][j]);
    __builtin_amdgcn_s_setprio(0);
  };

  STAGE(0); STAGE(1); STAGE(2);
  for (int k = 0; k < 38; k++) {
    asm volatile("s_waitcnt vmcnt(8)\n\ts_barrier" ::: "memory");
    if (k < 37) STAGE(k + 3);
    COMP(k);
  }
  asm volatile("s_waitcnt vmcnt(4)\n\ts_barrier" ::: "memory");
  COMP(38);
  asm volatile("s_waitcnt vmcnt(0)\n\ts_barrier" ::: "memory");
  COMP(39);

#pragma unroll
  for (int i = 0; i < 4; i++) {
    const int row_base = m0 + wm * 64 + i * 16 + lq * 4;
#pragma unroll
    for (int j = 0; j < 4; j++) {
      const int col = n0 + wn * 64 + j * 16 + lrow;
      const float bv = bias[col];
#pragma unroll
      for (int r = 0; r < 4; r++)
        C[(size_t)(row_base + r) * DIM + col] = acc[i][j][r] + bv;
    }
  }
}

// ---------------- launch ----------------
extern "C" void kernel_launch(void* const* d_in, const int* in_sizes, int n_in,
                              void* d_out, int out_size, void* d_ws, size_t ws_size,
                              hipStream_t stream) {
  const float* hidden = (const float*)d_in[0];
  // d_in[1] = cu_seqlens: fixed layout (32 chunks of 256), unused
  const float* cosb = (const float*)d_in[2];
  const float* sinb = (const float*)d_in[3];
  const float* w_qkv = (const float*)d_in[4];
  const float* b_qkv = (const float*)d_in[5];
  const float* w_proj = (const float*)d_in[6];
  const float* b_proj = (const float*)d_in[7];
  float* out = (float*)d_out;

  // workspace layout (bytes)
  char* ws = (char*)d_ws;
  constexpr size_t HB_B = (size_t)SEQ * DIM * 2;    // 20,971,520 hidden bf16
  constexpr size_t WQT_B = (size_t)NQKV * DIM * 2;  //  9,830,400 w_qkv^T bf16
  constexpr size_t WPT_B = (size_t)DIM * DIM * 2;   //  3,276,800 w_proj^T bf16
  constexpr size_t OB_B = (size_t)SEQ * DIM * 2;    // 20,971,520 attn out bf16
  size_t off = 0;
  unsigned short* hb = (unsigned short*)(ws + off);     off += HB_B;
  unsigned short* wqkvT = (unsigned short*)(ws + off);  off += WQT_B;
  unsigned short* wprojT = (unsigned short*)(ws + off); off += WPT_B;
  unsigned short* Ob = (unsigned short*)(ws + off);     off += OB_B;
  if (ws_size < off) return;

  // 1. cast hidden to bf16
  cast_bf16_kernel<<<dim3((SEQ * DIM / 4 + 255) / 256), dim3(256), 0, stream>>>(
      hidden, hb, SEQ * DIM / 4);
  // 2. transpose-cast weights
  transpose_cast_kernel<<<dim3(NQKV / 32, DIM / 32), dim3(256), 0, stream>>>(
      w_qkv, wqkvT, DIM, NQKV);
  transpose_cast_kernel<<<dim3(DIM / 32, DIM / 32), dim3(256), 0, stream>>>(
      w_proj, wprojT, DIM, DIM);
  // 3. mega: QKV GEMM + RoPE + attention -> Ob
  mega_attn<<<dim3(NIMG, HEADS), dim3(512), 0, stream>>>(hb, wqkvT, b_qkv, cosb, sinb, Ob);
  // 4. proj GEMM (+bias) -> d_out (f32)
  gemm_proj<<<dim3(SEQ / 128, DIM / 128), dim3(256), 0, stream>>>(
      Ob, wprojT, b_proj, out);
}

// Round 4
// 278.199 us; speedup vs baseline: 1.0323x; 1.0323x over previous
//
#include <hip/hip_runtime.h>
#include <stdint.h>

#define DEVFN __device__ __forceinline__

typedef short s16x8 __attribute__((ext_vector_type(8)));
typedef __bf16 bf16x8 __attribute__((ext_vector_type(8)));
typedef float fx4 __attribute__((ext_vector_type(4)));

// Problem constants (fixed by the reference)
constexpr int SEQ = 8192, DIM = 1280, HEADS = 16;
constexpr int NIMG = 32;
constexpr int NQKV = 3840;  // 3*DIM
constexpr int TS = 84;      // raw Q/K tile stride (168B rows: scatter = 2 lanes/bank, free)

DEVFN unsigned short f2bf(float f) {
  union { float f; unsigned u; } v; v.f = f;
  unsigned r = v.u + 0x7FFFu + ((v.u >> 16) & 1u);  // RNE
  return (unsigned short)(r >> 16);
}
DEVFN float bf2f(unsigned short u) {
  union { unsigned u; float f; } v; v.u = ((unsigned)u) << 16;
  return v.f;
}

DEVFN fx4 mfma16(s16x8 a, s16x8 b, fx4 c) {
  return __builtin_amdgcn_mfma_f32_16x16x32_bf16(
      __builtin_bit_cast(bf16x8, a), __builtin_bit_cast(bf16x8, b), c, 0, 0, 0);
}

DEVFN void gload_lds16(const void* g, void* l) {
  // global -> LDS direct, 16B per lane; LDS dest = wave-uniform base + lane*16
  __builtin_amdgcn_global_load_lds(
      (__attribute__((address_space(1))) void*)(uintptr_t)g,
      (__attribute__((address_space(3))) void*)l, 16, 0, 0);
}

// ---------------- f32 -> bf16 cast, 4 elems/thread ----------------
__global__ __launch_bounds__(256) void cast_bf16_kernel(const float* __restrict__ in,
                                                        unsigned short* __restrict__ out,
                                                        int n4) {
  int i = blockIdx.x * 256 + threadIdx.x;
  if (i >= n4) return;
  float4 v = ((const float4*)in)[i];
  ushort4 o;
  o.x = f2bf(v.x); o.y = f2bf(v.y); o.z = f2bf(v.z); o.w = f2bf(v.w);
  ((ushort4*)out)[i] = o;
}

// ---------------- transpose + cast: T[n][k] = W[k][n], bf16 out ----------------
__global__ __launch_bounds__(256) void transpose_cast_kernel(const float* __restrict__ W,
                                                             unsigned short* __restrict__ T,
                                                             int K, int N) {
  __shared__ float tile[32][33];
  const int tx = threadIdx.x & 31, ty = threadIdx.x >> 5;  // 32x8
  const int n0 = blockIdx.x * 32, k0 = blockIdx.y * 32;
#pragma unroll
  for (int i = 0; i < 4; i++) {
    int r = ty + i * 8;
    tile[r][tx] = W[(size_t)(k0 + r) * N + n0 + tx];
  }
  __syncthreads();
#pragma unroll
  for (int i = 0; i < 4; i++) {
    int r = ty + i * 8;
    T[(size_t)(n0 + r) * K + k0 + tx] = f2bf(tile[tx][r]);
  }
}

// ---------------- mega kernel: QKV GEMM + bias + RoPE + attention ----------------
// Block = (img n, head h), 512 threads = 8 waves (4x2). GEMM: 256x256x1280.
// BK=32 quad-buffer ring (4 x 16KB per matrix, 128KB), depth-3 prefetch with
// counted s_waitcnt vmcnt(8) (never 0 in steady state, T3/T4) + s_setprio around
// the MFMA cluster (T5). Measured round 3: 129us, MfmaUtil 31.5 (vs 174/28 dbuf).
// LDS tile rows are 64B; chunk position XOR-swizzled by (row>>1)&3.
// Epilogue scatters acc+bias branchlessly into raw Q/K (stride 84) and V directly
// transposed into Vt[80][264]; then rope + QK^T + softmax + PV.
// LDS (153600 B): ring Abuf 4x16K @0, Bbuf 4x16K @65536 (dead after K-loop);
// X@0 (rawK84 -> Ks[256][104] -> P-scratch 8x16x264), Y@67584 (rawQ84),
// Vt@110592 (80x264, written in epilogue, read by PV).
__global__ __launch_bounds__(512, 2) void mega_attn(const unsigned short* __restrict__ hb,
                                                    const unsigned short* __restrict__ wqkvT,
                                                    const float* __restrict__ b_qkv,
                                                    const float* __restrict__ cosb,
                                                    const float* __restrict__ sinb,
                                                    unsigned short* __restrict__ Ob) {
  __shared__ __attribute__((aligned(16))) char smem[153600];
  unsigned short* X = (unsigned short*)smem;
  unsigned short* Y = (unsigned short*)(smem + 67584);
  unsigned short* Vt = (unsigned short*)(smem + 110592);  // [80][264]
  char* Abuf = smem;          // 4 x 16384
  char* Bbuf = smem + 65536;  // 4 x 16384

  const int t = threadIdx.x;
  const int lane = t & 63, w = t >> 6;
  const int lrow = lane & 15, lq = lane >> 4;
  const int n = blockIdx.x, h = blockIdx.y;
  const int s0 = n * 256;
  const int wm = w >> 1, wn = w & 1;

  // staging geometry (BK=32): per matrix 1024 16B-chunks/step (256 rows x 4 chunks);
  // thread covers slots t and t+512. slot s -> row r = s>>2, pos p = s&3; stored pos p
  // holds global chunk p ^ ((r>>1)&3)  (swizzle -> ~2-way banks on ds_read_b128).
  const int tr2 = t >> 2;  // 0..127
  const int g8 = ((t & 3) ^ ((t >> 3) & 3)) * 8;
  const unsigned short* pA32[2];
  pA32[0] = hb + (size_t)(s0 + tr2) * 1280 + g8;
  pA32[1] = pA32[0] + (size_t)128 * 1280;
  const unsigned short* pB32[2];
#pragma unroll
  for (int i = 0; i < 2; i++) {
    const int r = tr2 + i * 128;
    const int rr = r < 240 ? r : 239;  // pad rows clamp (cols 240..255 never used)
    const int sgm = (rr >= 160) ? 2 : (rr >= 80 ? 1 : 0);
    pB32[i] = wqkvT + (size_t)(sgm * DIM + h * 80 + (rr - sgm * 80)) * 1280 + g8;
  }

  // fragment read offsets: row ra, chunk lq ^ ((ra>>1)&3); (ra>>1)&3 == (lrow>>1)&3.
  const int swzr = (lq ^ ((lrow >> 1) & 3)) * 16;
  int offA32[4], offB32[8];
#pragma unroll
  for (int i = 0; i < 4; i++) offA32[i] = (wm * 64 + i * 16 + lrow) * 64 + swzr;
#pragma unroll
  for (int j = 0; j < 8; j++) offB32[j] = (wn * 128 + j * 16 + lrow) * 64 + swzr;

  fx4 acc[4][8] = {};

  auto STAGE = [&](int k) {
    const int kof = k * 32;
    char* da = Abuf + (k & 3) * 16384 + w * 1024;
    char* db = Bbuf + (k & 3) * 16384 + w * 1024;
    gload_lds16(pA32[0] + kof, da);
    gload_lds16(pB32[0] + kof, db);
    gload_lds16(pA32[1] + kof, da + 8192);
    gload_lds16(pB32[1] + kof, db + 8192);
  };
  auto COMP = [&](int k) {
    const char* As = Abuf + (k & 3) * 16384;
    const char* Bs = Bbuf + (k & 3) * 16384;
    s16x8 a[4], b[8];
#pragma unroll
    for (int i = 0; i < 4; i++) a[i] = *(const s16x8*)(As + offA32[i]);
#pragma unroll
    for (int j = 0; j < 8; j++) b[j] = *(const s16x8*)(Bs + offB32[j]);
    __builtin_amdgcn_s_setprio(1);
#pragma unroll
    for (int i = 0; i < 4; i++)
#pragma unroll
      for (int j = 0; j < 8; j++)
        acc[i][j] = mfma16(a[i], b[j], acc[i][j]);
    __builtin_amdgcn_s_setprio(0);
  };

  // prologue: 3 K-steps in flight (12 loads/thread)
  STAGE(0); STAGE(1); STAGE(2);
  // main loop: each wave waits only its own oldest 4 loads (buf k) -> after the
  // barrier every wave's buf[k] is complete; bufs k+1,k+2 stay in flight ACROSS
  // the barrier (counted vmcnt, T4). Issuing buf[k+3] overwrites buf[k-1], which
  // all waves finished reading before this barrier.
  for (int k = 0; k < 38; k++) {
    asm volatile("s_waitcnt vmcnt(8)\n\ts_barrier" ::: "memory");
    if (k < 37) STAGE(k + 3);
    COMP(k);
  }
  asm volatile("s_waitcnt vmcnt(4)\n\ts_barrier" ::: "memory");
  COMP(38);
  asm volatile("s_waitcnt vmcnt(0)\n\ts_barrier" ::: "memory");
  COMP(39);
  __syncthreads();  // all fragment reads done before staging regions become Q/K/Vt

  // ---- epilogue scatter (branchless stride-select): acc + bias ->
  //      sgm 0/1: raw Q (Y) / K (X), addr = row*84 + d
  //      sgm 2:   Vt transposed,      addr = d*264 + row
#pragma unroll
  for (int j = 0; j < 8; j++) {
    const int col = wn * 128 + j * 16 + lrow;
    if (col < 240) {
      const int sgm = (col >= 160) ? 2 : (col >= 80 ? 1 : 0);
      const int d = col - sgm * 80;
      const float bv = b_qkv[sgm * DIM + h * 80 + d];
      unsigned short* dst = (sgm == 0) ? Y : (sgm == 1) ? X : Vt;
      const int rs = (sgm == 2) ? 1 : TS;
      const int dd = (sgm == 2) ? 264 : 1;
      const int dbase = d * dd;
#pragma unroll
      for (int i = 0; i < 4; i++) {
        const int row = wm * 64 + i * 16 + lq * 4;
#pragma unroll
        for (int r = 0; r < 4; r++)
          dst[(row + r) * rs + dbase] = f2bf(acc[i][j][r] + bv);
      }
    }
  }
  __syncthreads();  // B1: raw Q/K + Vt complete

  // ---- K rope -> regs; Q rope -> A-fragments (wave w owns q-rows w*32..w*32+31) ----
  unsigned short kout[5][8];
  int kro[5], kco[5];
#pragma unroll
  for (int i = 0; i < 5; i++) {
    const int idx = t + i * 512;
    const unsigned r = (unsigned)idx / 10u, c = (unsigned)idx % 10u;
    kro[i] = r; kco[i] = c;
    s16x8 xv = *(const s16x8*)&X[r * TS + c * 8];
    const unsigned cp = (c < 5) ? c + 5 : c - 5;  // partner chunk (+-40 elems)
    s16x8 pv = *(const s16x8*)&X[r * TS + cp * 8];
    const float sgn = (c < 5) ? -1.f : 1.f;
    const float* cf = cosb + (size_t)(s0 + r) * 80 + c * 8;
    const float* sf = sinb + (size_t)(s0 + r) * 80 + c * 8;
#pragma unroll
    for (int j = 0; j < 8; j++)
      kout[i][j] = f2bf(bf2f((unsigned short)xv[j]) * cf[j] +
                        sgn * bf2f((unsigned short)pv[j]) * sf[j]);
  }

  s16x8 aq[2][3];
#pragma unroll
  for (int rt = 0; rt < 2; rt++) {
#pragma unroll
    for (int c = 0; c < 3; c++) {
      const int row = w * 32 + rt * 16 + lrow;
      const int d0 = c * 32 + lq * 8;
      s16x8 fr = {};
      if (d0 < 80) {
        s16x8 xv = *(const s16x8*)&Y[row * TS + d0];
        const int dp = (d0 < 40) ? d0 + 40 : d0 - 40;
        s16x8 pv = *(const s16x8*)&Y[row * TS + dp];
        const float sgn = (d0 < 40) ? -1.f : 1.f;
        const float* cf = cosb + (size_t)(s0 + row) * 80 + d0;
        const float* sf = sinb + (size_t)(s0 + row) * 80 + d0;
#pragma unroll
        for (int j = 0; j < 8; j++)
          fr[j] = (short)f2bf(bf2f((unsigned short)xv[j]) * cf[j] +
                              sgn * bf2f((unsigned short)pv[j]) * sf[j]);
      }
      aq[rt][c] = fr;
    }
  }
  __syncthreads();  // B2: rawK/rawQ reads done

  // ---- write rope'd K at stride 104 (2-way bank aliasing = free) + zero pad ----
#pragma unroll
  for (int i = 0; i < 5; i++)
    *(int4*)&X[kro[i] * 104 + kco[i] * 8] = *(const int4*)kout[i];
  {
    const int r = t >> 1, wh = t & 1;
    const int4 z = {0, 0, 0, 0};
    *(int4*)&X[r * 104 + 80 + wh * 8] = z;
  }
  __syncthreads();  // B3

  // ---- QK^T: 2 row-tiles x 16 col-tiles, K = 96 ----
  fx4 acc2[2][16] = {};
#pragma unroll
  for (int c = 0; c < 3; c++) {
#pragma unroll
    for (int ct = 0; ct < 16; ct++) {
      s16x8 b = *(const s16x8*)&X[(ct * 16 + lrow) * 104 + c * 32 + lq * 8];
      acc2[0][ct] = mfma16(aq[0][c], b, acc2[0][ct]);
      acc2[1][ct] = mfma16(aq[1][c], b, acc2[1][ct]);
    }
  }

  // ---- softmax (rows wave-local: row = rt*16 + lq*4 + r) ----
  const float kscale = 0.11180339887498949f * 1.4426950408889634f;  // 80^-0.5 * log2e
  float inv[2][4];
#pragma unroll
  for (int rt = 0; rt < 2; rt++) {
    float mx[4] = {-1e30f, -1e30f, -1e30f, -1e30f};
#pragma unroll
    for (int ct = 0; ct < 16; ct++)
#pragma unroll
      for (int r = 0; r < 4; r++) mx[r] = fmaxf(mx[r], acc2[rt][ct][r]);
#pragma unroll
    for (int r = 0; r < 4; r++) {
      mx[r] = fmaxf(mx[r], __shfl_xor(mx[r], 1));
      mx[r] = fmaxf(mx[r], __shfl_xor(mx[r], 2));
      mx[r] = fmaxf(mx[r], __shfl_xor(mx[r], 4));
      mx[r] = fmaxf(mx[r], __shfl_xor(mx[r], 8));
    }
    float sm[4] = {0.f, 0.f, 0.f, 0.f};
#pragma unroll
    for (int ct = 0; ct < 16; ct++)
#pragma unroll
      for (int r = 0; r < 4; r++) {
        float e = exp2f((acc2[rt][ct][r] - mx[r]) * kscale);
        acc2[rt][ct][r] = e;
        sm[r] += e;
      }
#pragma unroll
    for (int r = 0; r < 4; r++) {
      sm[r] += __shfl_xor(sm[r], 1);
      sm[r] += __shfl_xor(sm[r], 2);
      sm[r] += __shfl_xor(sm[r], 4);
      sm[r] += __shfl_xor(sm[r], 8);
      inv[rt][r] = 1.f / sm[r];
    }
  }
  __syncthreads();  // B4: Ks dead; X becomes per-wave P-scratch

  // ---- P (rt=0) to per-wave scratch (wave-private: only lgkmcnt ordering needed,
  //      compiler inserts it; Vt has been complete since B1 -> no barrier here) ----
  unsigned short* Pw = X + w * 4224;  // 16 rows x 264 elems
#pragma unroll
  for (int ct = 0; ct < 16; ct++)
#pragma unroll
    for (int r = 0; r < 4; r++)
      Pw[(lq * 4 + r) * 264 + ct * 16 + lrow] = f2bf(acc2[0][ct][r] * inv[0][r]);

  // ---- PV + output, two 16-row sweeps ----
#pragma unroll
  for (int rt = 0; rt < 2; rt++) {
    if (rt == 1) {
#pragma unroll
      for (int ct = 0; ct < 16; ct++)
#pragma unroll
        for (int r = 0; r < 4; r++)
          Pw[(lq * 4 + r) * 264 + ct * 16 + lrow] = f2bf(acc2[1][ct][r] * inv[1][r]);
    }
    fx4 accO[5] = {};
#pragma unroll
    for (int kc = 0; kc < 8; kc++) {
      s16x8 a = *(const s16x8*)&Pw[lrow * 264 + kc * 32 + lq * 8];
#pragma unroll
      for (int tt = 0; tt < 5; tt++) {
        s16x8 b = *(const s16x8*)&Vt[(tt * 16 + lrow) * 264 + kc * 32 + lq * 8];
        accO[tt] = mfma16(a, b, accO[tt]);
      }
    }
    const int srow = s0 + w * 32 + rt * 16 + lq * 4;
#pragma unroll
    for (int tt = 0; tt < 5; tt++) {
      const int col = h * 80 + tt * 16 + lrow;
#pragma unroll
      for (int r = 0; r < 4; r++)
        Ob[(size_t)(srow + r) * DIM + col] = f2bf(accO[tt][r]);
    }
  }
}

// ---------------- proj GEMM: 128x128, BK=64, LDS-DMA double-buffered ----------------
// Round-2-measured best for proj (~83us): global_load_lds width-16 + XOR-8 swizzle,
// raw vmcnt(0)+s_barrier per K-step, loads for k+1 in flight during compute k.
// (BK=32 counted-vmcnt ring REGRESSED proj to ~142us in round 3: 4 waves x 16 MFMA
// per step is too short to cover the doubled barrier/issue overhead. Do not re-apply.)
// LDS 64 KB -> 2 blocks/CU.
__global__ __launch_bounds__(256, 2) void gemm_proj(const unsigned short* __restrict__ A,
                                                    const unsigned short* __restrict__ Bt,
                                                    const float* __restrict__ bias,
                                                    float* __restrict__ C) {
  __shared__ __attribute__((aligned(16))) char smem[65536];
  char* Abuf = smem;          // 2 x 16384
  char* Bbuf = smem + 32768;  // 2 x 16384
  const int t = threadIdx.x;
  const int lane = t & 63, w = t >> 6;
  const int lrow = lane & 15, lq = lane >> 4;
  const int l7 = lrow & 7;
  const int wm = w >> 1, wn = w & 1;  // 2x2 wave grid, 64x64 tiles
  const int m0 = blockIdx.x * 128, n0 = blockIdx.y * 128;

  // staging: per matrix 1024 16B-chunks/iter; thread covers slots i*256+t (i=0..3).
  // slot s -> row r = s>>3 = i*32 + (t>>3); stored chunk t&7 = global (t&7)^(r&7).
  const int tr3 = t >> 3;
  const int cchunk = ((t & 7) ^ (tr3 & 7)) * 8;
  const unsigned short* pA = A + (size_t)(m0 + tr3) * 1280 + cchunk;
  const unsigned short* pBt = Bt + (size_t)(n0 + tr3) * 1280 + cchunk;

  int offA[4][2], offB[4][2];
#pragma unroll
  for (int i = 0; i < 4; i++) {
    const int ra = wm * 64 + i * 16 + lrow;
    const int rb = wn * 64 + i * 16 + lrow;
    offA[i][0] = ra * 128 + (lq ^ l7) * 16;
    offA[i][1] = ra * 128 + ((lq + 4) ^ l7) * 16;
    offB[i][0] = rb * 128 + (lq ^ l7) * 16;
    offB[i][1] = rb * 128 + ((lq + 4) ^ l7) * 16;
  }

  fx4 acc[4][4] = {};

  // prologue: stage k=0 into buf0
  {
    char* da = Abuf + w * 1024;
    char* db = Bbuf + w * 1024;
#pragma unroll
    for (int i = 0; i < 4; i++) {
      gload_lds16(pA + (size_t)i * 32 * 1280, da + i * 4096);
      gload_lds16(pBt + (size_t)i * 32 * 1280, db + i * 4096);
    }
  }

  for (int k = 0; k < 20; k++) {
    asm volatile("s_waitcnt vmcnt(0)\n\ts_barrier" ::: "memory");
    if (k < 19) {  // issue buf[k+1]; flies during compute(k)
      const int kof = (k + 1) * 64;
      char* da = Abuf + ((k + 1) & 1) * 16384 + w * 1024;
      char* db = Bbuf + ((k + 1) & 1) * 16384 + w * 1024;
#pragma unroll
      for (int i = 0; i < 4; i++) {
        gload_lds16(pA + (size_t)i * 32 * 1280 + kof, da + i * 4096);
        gload_lds16(pBt + (size_t)i * 32 * 1280 + kof, db + i * 4096);
      }
    }
    const char* As = Abuf + (k & 1) * 16384;
    const char* Bs = Bbuf + (k & 1) * 16384;
#pragma unroll
    for (int kq = 0; kq < 2; kq++) {
      s16x8 a[4], b[4];
#pragma unroll
      for (int i = 0; i < 4; i++) a[i] = *(const s16x8*)(As + offA[i][kq]);
#pragma unroll
      for (int j = 0; j < 4; j++) b[j] = *(const s16x8*)(Bs + offB[j][kq]);
#pragma unroll
      for (int i = 0; i < 4; i++)
#pragma unroll
        for (int j = 0; j < 4; j++)
          acc[i][j] = mfma16(a[i], b[j], acc[i][j]);
    }
  }

#pragma unroll
  for (int i = 0; i < 4; i++) {
    const int row_base = m0 + wm * 64 + i * 16 + lq * 4;
#pragma unroll
    for (int j = 0; j < 4; j++) {
      const int col = n0 + wn * 64 + j * 16 + lrow;
      const float bv = bias[col];
#pragma unroll
      for (int r = 0; r < 4; r++)
        C[(size_t)(row_base + r) * DIM + col] = acc[i][j][r] + bv;
    }
  }
}

// ---------------- launch ----------------
extern "C" void kernel_launch(void* const* d_in, const int* in_sizes, int n_in,
                              void* d_out, int out_size, void* d_ws, size_t ws_size,
                              hipStream_t stream) {
  const float* hidden = (const float*)d_in[0];
  // d_in[1] = cu_seqlens: fixed layout (32 chunks of 256), unused
  const float* cosb = (const float*)d_in[2];
  const float* sinb = (const float*)d_in[3];
  const float* w_qkv = (const float*)d_in[4];
  const float* b_qkv = (const float*)d_in[5];
  const float* w_proj = (const float*)d_in[6];
  const float* b_proj = (const float*)d_in[7];
  float* out = (float*)d_out;

  // workspace layout (bytes)
  char* ws = (char*)d_ws;
  constexpr size_t HB_B = (size_t)SEQ * DIM * 2;    // 20,971,520 hidden bf16
  constexpr size_t WQT_B = (size_t)NQKV * DIM * 2;  //  9,830,400 w_qkv^T bf16
  constexpr size_t WPT_B = (size_t)DIM * DIM * 2;   //  3,276,800 w_proj^T bf16
  constexpr size_t OB_B = (size_t)SEQ * DIM * 2;    // 20,971,520 attn out bf16
  size_t off = 0;
  unsigned short* hb = (unsigned short*)(ws + off);     off += HB_B;
  unsigned short* wqkvT = (unsigned short*)(ws + off);  off += WQT_B;
  unsigned short* wprojT = (unsigned short*)(ws + off); off += WPT_B;
  unsigned short* Ob = (unsigned short*)(ws + off);     off += OB_B;
  if (ws_size < off) return;

  // 1. cast hidden to bf16
  cast_bf16_kernel<<<dim3((SEQ * DIM / 4 + 255) / 256), dim3(256), 0, stream>>>(
      hidden, hb, SEQ * DIM / 4);
  // 2. transpose-cast weights
  transpose_cast_kernel<<<dim3(NQKV / 32, DIM / 32), dim3(256), 0, stream>>>(
      w_qkv, wqkvT, DIM, NQKV);
  transpose_cast_kernel<<<dim3(DIM / 32, DIM / 32), dim3(256), 0, stream>>>(
      w_proj, wprojT, DIM, DIM);
  // 3. mega: QKV GEMM + RoPE + attention -> Ob
  mega_attn<<<dim3(NIMG, HEADS), dim3(512), 0, stream>>>(hb, wqkvT, b_qkv, cosb, sinb, Ob);
  // 4. proj GEMM (+bias) -> d_out (f32)
  gemm_proj<<<dim3(SEQ / 128, DIM / 128), dim3(256), 0, stream>>>(
      Ob, wprojT, b_proj, out);
}

// Round 5
// 277.752 us; speedup vs baseline: 1.0339x; 1.0016x over previous
//
#include <hip/hip_runtime.h>
#include <stdint.h>

#define DEVFN __device__ __forceinline__

typedef short s16x8 __attribute__((ext_vector_type(8)));
typedef __bf16 bf16x8 __attribute__((ext_vector_type(8)));
typedef float fx4 __attribute__((ext_vector_type(4)));

// Problem constants (fixed by the reference)
constexpr int SEQ = 8192, DIM = 1280, HEADS = 16;
constexpr int NIMG = 32;
constexpr int NQKV = 3840;  // 3*DIM
constexpr int TS = 84;      // raw Q/K tile stride (168B rows: scatter = 2 lanes/bank, free)

DEVFN unsigned short f2bf(float f) {
  union { float f; unsigned u; } v; v.f = f;
  unsigned r = v.u + 0x7FFFu + ((v.u >> 16) & 1u);  // RNE
  return (unsigned short)(r >> 16);
}
DEVFN float bf2f(unsigned short u) {
  union { unsigned u; float f; } v; v.u = ((unsigned)u) << 16;
  return v.f;
}

DEVFN fx4 mfma16(s16x8 a, s16x8 b, fx4 c) {
  return __builtin_amdgcn_mfma_f32_16x16x32_bf16(
      __builtin_bit_cast(bf16x8, a), __builtin_bit_cast(bf16x8, b), c, 0, 0, 0);
}

DEVFN void gload_lds16(const void* g, void* l) {
  // global -> LDS direct, 16B per lane; LDS dest = wave-uniform base + lane*16
  __builtin_amdgcn_global_load_lds(
      (__attribute__((address_space(1))) void*)(uintptr_t)g,
      (__attribute__((address_space(3))) void*)l, 16, 0, 0);
}

// ---------------- f32 -> bf16 cast, 4 elems/thread ----------------
__global__ __launch_bounds__(256) void cast_bf16_kernel(const float* __restrict__ in,
                                                        unsigned short* __restrict__ out,
                                                        int n4) {
  int i = blockIdx.x * 256 + threadIdx.x;
  if (i >= n4) return;
  float4 v = ((const float4*)in)[i];
  ushort4 o;
  o.x = f2bf(v.x); o.y = f2bf(v.y); o.z = f2bf(v.z); o.w = f2bf(v.w);
  ((ushort4*)out)[i] = o;
}

// ---------------- transpose + cast: T[n][k] = W[k][n], bf16 out ----------------
__global__ __launch_bounds__(256) void transpose_cast_kernel(const float* __restrict__ W,
                                                             unsigned short* __restrict__ T,
                                                             int K, int N) {
  __shared__ float tile[32][33];
  const int tx = threadIdx.x & 31, ty = threadIdx.x >> 5;  // 32x8
  const int n0 = blockIdx.x * 32, k0 = blockIdx.y * 32;
#pragma unroll
  for (int i = 0; i < 4; i++) {
    int r = ty + i * 8;
    tile[r][tx] = W[(size_t)(k0 + r) * N + n0 + tx];
  }
  __syncthreads();
#pragma unroll
  for (int i = 0; i < 4; i++) {
    int r = ty + i * 8;
    T[(size_t)(n0 + r) * K + k0 + tx] = f2bf(tile[tx][r]);
  }
}

// ---------------- mega kernel: QKV GEMM + bias + RoPE + attention ----------------
// FROZEN from round 3/4 (measured 129-134us, MfmaUtil ~31.5). Block = (img n, head
// h), 512 threads = 8 waves (4x2). GEMM: 256x256x1280, BK=32 quad-buffer ring
// (4 x 16KB per matrix), depth-3 prefetch, counted s_waitcnt vmcnt(8) (T3/T4),
// s_setprio around MFMA (T5). Epilogue scatters acc+bias branchlessly into raw Q/K
// (stride 84) and V directly transposed into Vt[80][264]; then rope+QK^T+softmax+PV.
// LDS (153600 B): ring Abuf 4x16K @0, Bbuf 4x16K @65536 (dead after K-loop);
// X@0 (rawK84 -> Ks[256][104] -> P-scratch 8x16x264), Y@67584 (rawQ84),
// Vt@110592 (80x264).
__global__ __launch_bounds__(512, 2) void mega_attn(const unsigned short* __restrict__ hb,
                                                    const unsigned short* __restrict__ wqkvT,
                                                    const float* __restrict__ b_qkv,
                                                    const float* __restrict__ cosb,
                                                    const float* __restrict__ sinb,
                                                    unsigned short* __restrict__ Ob) {
  __shared__ __attribute__((aligned(16))) char smem[153600];
  unsigned short* X = (unsigned short*)smem;
  unsigned short* Y = (unsigned short*)(smem + 67584);
  unsigned short* Vt = (unsigned short*)(smem + 110592);  // [80][264]
  char* Abuf = smem;          // 4 x 16384
  char* Bbuf = smem + 65536;  // 4 x 16384

  const int t = threadIdx.x;
  const int lane = t & 63, w = t >> 6;
  const int lrow = lane & 15, lq = lane >> 4;
  const int n = blockIdx.x, h = blockIdx.y;
  const int s0 = n * 256;
  const int wm = w >> 1, wn = w & 1;

  // staging geometry (BK=32): per matrix 1024 16B-chunks/step (256 rows x 4 chunks);
  // thread covers slots t and t+512. slot s -> row r = s>>2, pos p = s&3; stored pos p
  // holds global chunk p ^ ((r>>1)&3)  (swizzle -> ~2-way banks on ds_read_b128).
  const int tr2 = t >> 2;  // 0..127
  const int g8 = ((t & 3) ^ ((t >> 3) & 3)) * 8;
  const unsigned short* pA32[2];
  pA32[0] = hb + (size_t)(s0 + tr2) * 1280 + g8;
  pA32[1] = pA32[0] + (size_t)128 * 1280;
  const unsigned short* pB32[2];
#pragma unroll
  for (int i = 0; i < 2; i++) {
    const int r = tr2 + i * 128;
    const int rr = r < 240 ? r : 239;  // pad rows clamp (cols 240..255 never used)
    const int sgm = (rr >= 160) ? 2 : (rr >= 80 ? 1 : 0);
    pB32[i] = wqkvT + (size_t)(sgm * DIM + h * 80 + (rr - sgm * 80)) * 1280 + g8;
  }

  // fragment read offsets: row ra, chunk lq ^ ((ra>>1)&3); (ra>>1)&3 == (lrow>>1)&3.
  const int swzr = (lq ^ ((lrow >> 1) & 3)) * 16;
  int offA32[4], offB32[8];
#pragma unroll
  for (int i = 0; i < 4; i++) offA32[i] = (wm * 64 + i * 16 + lrow) * 64 + swzr;
#pragma unroll
  for (int j = 0; j < 8; j++) offB32[j] = (wn * 128 + j * 16 + lrow) * 64 + swzr;

  fx4 acc[4][8] = {};

  auto STAGE = [&](int k) {
    const int kof = k * 32;
    char* da = Abuf + (k & 3) * 16384 + w * 1024;
    char* db = Bbuf + (k & 3) * 16384 + w * 1024;
    gload_lds16(pA32[0] + kof, da);
    gload_lds16(pB32[0] + kof, db);
    gload_lds16(pA32[1] + kof, da + 8192);
    gload_lds16(pB32[1] + kof, db + 8192);
  };
  auto COMP = [&](int k) {
    const char* As = Abuf + (k & 3) * 16384;
    const char* Bs = Bbuf + (k & 3) * 16384;
    s16x8 a[4], b[8];
#pragma unroll
    for (int i = 0; i < 4; i++) a[i] = *(const s16x8*)(As + offA32[i]);
#pragma unroll
    for (int j = 0; j < 8; j++) b[j] = *(const s16x8*)(Bs + offB32[j]);
    __builtin_amdgcn_s_setprio(1);
#pragma unroll
    for (int i = 0; i < 4; i++)
#pragma unroll
      for (int j = 0; j < 8; j++)
        acc[i][j] = mfma16(a[i], b[j], acc[i][j]);
    __builtin_amdgcn_s_setprio(0);
  };

  // prologue: 3 K-steps in flight (12 loads/thread)
  STAGE(0); STAGE(1); STAGE(2);
  // main loop: wait own oldest 4 loads (buf k) -> after barrier everyone's buf[k]
  // is complete; bufs k+1,k+2 stay in flight ACROSS the barrier (counted vmcnt).
  for (int k = 0; k < 38; k++) {
    asm volatile("s_waitcnt vmcnt(8)\n\ts_barrier" ::: "memory");
    if (k < 37) STAGE(k + 3);
    COMP(k);
  }
  asm volatile("s_waitcnt vmcnt(4)\n\ts_barrier" ::: "memory");
  COMP(38);
  asm volatile("s_waitcnt vmcnt(0)\n\ts_barrier" ::: "memory");
  COMP(39);
  __syncthreads();  // all fragment reads done before staging regions become Q/K/Vt

  // ---- epilogue scatter (branchless stride-select): acc + bias ->
  //      sgm 0/1: raw Q (Y) / K (X), addr = row*84 + d
  //      sgm 2:   Vt transposed,      addr = d*264 + row
#pragma unroll
  for (int j = 0; j < 8; j++) {
    const int col = wn * 128 + j * 16 + lrow;
    if (col < 240) {
      const int sgm = (col >= 160) ? 2 : (col >= 80 ? 1 : 0);
      const int d = col - sgm * 80;
      const float bv = b_qkv[sgm * DIM + h * 80 + d];
      unsigned short* dst = (sgm == 0) ? Y : (sgm == 1) ? X : Vt;
      const int rs = (sgm == 2) ? 1 : TS;
      const int dd = (sgm == 2) ? 264 : 1;
      const int dbase = d * dd;
#pragma unroll
      for (int i = 0; i < 4; i++) {
        const int row = wm * 64 + i * 16 + lq * 4;
#pragma unroll
        for (int r = 0; r < 4; r++)
          dst[(row + r) * rs + dbase] = f2bf(acc[i][j][r] + bv);
      }
    }
  }
  __syncthreads();  // B1: raw Q/K + Vt complete

  // ---- K rope -> regs; Q rope -> A-fragments (wave w owns q-rows w*32..w*32+31) ----
  unsigned short kout[5][8];
  int kro[5], kco[5];
#pragma unroll
  for (int i = 0; i < 5; i++) {
    const int idx = t + i * 512;
    const unsigned r = (unsigned)idx / 10u, c = (unsigned)idx % 10u;
    kro[i] = r; kco[i] = c;
    s16x8 xv = *(const s16x8*)&X[r * TS + c * 8];
    const unsigned cp = (c < 5) ? c + 5 : c - 5;  // partner chunk (+-40 elems)
    s16x8 pv = *(const s16x8*)&X[r * TS + cp * 8];
    const float sgn = (c < 5) ? -1.f : 1.f;
    const float* cf = cosb + (size_t)(s0 + r) * 80 + c * 8;
    const float* sf = sinb + (size_t)(s0 + r) * 80 + c * 8;
#pragma unroll
    for (int j = 0; j < 8; j++)
      kout[i][j] = f2bf(bf2f((unsigned short)xv[j]) * cf[j] +
                        sgn * bf2f((unsigned short)pv[j]) * sf[j]);
  }

  s16x8 aq[2][3];
#pragma unroll
  for (int rt = 0; rt < 2; rt++) {
#pragma unroll
    for (int c = 0; c < 3; c++) {
      const int row = w * 32 + rt * 16 + lrow;
      const int d0 = c * 32 + lq * 8;
      s16x8 fr = {};
      if (d0 < 80) {
        s16x8 xv = *(const s16x8*)&Y[row * TS + d0];
        const int dp = (d0 < 40) ? d0 + 40 : d0 - 40;
        s16x8 pv = *(const s16x8*)&Y[row * TS + dp];
        const float sgn = (d0 < 40) ? -1.f : 1.f;
        const float* cf = cosb + (size_t)(s0 + row) * 80 + d0;
        const float* sf = sinb + (size_t)(s0 + row) * 80 + d0;
#pragma unroll
        for (int j = 0; j < 8; j++)
          fr[j] = (short)f2bf(bf2f((unsigned short)xv[j]) * cf[j] +
                              sgn * bf2f((unsigned short)pv[j]) * sf[j]);
      }
      aq[rt][c] = fr;
    }
  }
  __syncthreads();  // B2: rawK/rawQ reads done

  // ---- write rope'd K at stride 104 (2-way bank aliasing = free) + zero pad ----
#pragma unroll
  for (int i = 0; i < 5; i++)
    *(int4*)&X[kro[i] * 104 + kco[i] * 8] = *(const int4*)kout[i];
  {
    const int r = t >> 1, wh = t & 1;
    const int4 z = {0, 0, 0, 0};
    *(int4*)&X[r * 104 + 80 + wh * 8] = z;
  }
  __syncthreads();  // B3

  // ---- QK^T: 2 row-tiles x 16 col-tiles, K = 96 ----
  fx4 acc2[2][16] = {};
#pragma unroll
  for (int c = 0; c < 3; c++) {
#pragma unroll
    for (int ct = 0; ct < 16; ct++) {
      s16x8 b = *(const s16x8*)&X[(ct * 16 + lrow) * 104 + c * 32 + lq * 8];
      acc2[0][ct] = mfma16(aq[0][c], b, acc2[0][ct]);
      acc2[1][ct] = mfma16(aq[1][c], b, acc2[1][ct]);
    }
  }

  // ---- softmax (rows wave-local: row = rt*16 + lq*4 + r) ----
  const float kscale = 0.11180339887498949f * 1.4426950408889634f;  // 80^-0.5 * log2e
  float inv[2][4];
#pragma unroll
  for (int rt = 0; rt < 2; rt++) {
    float mx[4] = {-1e30f, -1e30f, -1e30f, -1e30f};
#pragma unroll
    for (int ct = 0; ct < 16; ct++)
#pragma unroll
      for (int r = 0; r < 4; r++) mx[r] = fmaxf(mx[r], acc2[rt][ct][r]);
#pragma unroll
    for (int r = 0; r < 4; r++) {
      mx[r] = fmaxf(mx[r], __shfl_xor(mx[r], 1));
      mx[r] = fmaxf(mx[r], __shfl_xor(mx[r], 2));
      mx[r] = fmaxf(mx[r], __shfl_xor(mx[r], 4));
      mx[r] = fmaxf(mx[r], __shfl_xor(mx[r], 8));
    }
    float sm[4] = {0.f, 0.f, 0.f, 0.f};
#pragma unroll
    for (int ct = 0; ct < 16; ct++)
#pragma unroll
      for (int r = 0; r < 4; r++) {
        float e = exp2f((acc2[rt][ct][r] - mx[r]) * kscale);
        acc2[rt][ct][r] = e;
        sm[r] += e;
      }
#pragma unroll
    for (int r = 0; r < 4; r++) {
      sm[r] += __shfl_xor(sm[r], 1);
      sm[r] += __shfl_xor(sm[r], 2);
      sm[r] += __shfl_xor(sm[r], 4);
      sm[r] += __shfl_xor(sm[r], 8);
      inv[rt][r] = 1.f / sm[r];
    }
  }
  __syncthreads();  // B4: Ks dead; X becomes per-wave P-scratch

  // ---- P (rt=0) to per-wave scratch (wave-private; Vt complete since B1) ----
  unsigned short* Pw = X + w * 4224;  // 16 rows x 264 elems
#pragma unroll
  for (int ct = 0; ct < 16; ct++)
#pragma unroll
    for (int r = 0; r < 4; r++)
      Pw[(lq * 4 + r) * 264 + ct * 16 + lrow] = f2bf(acc2[0][ct][r] * inv[0][r]);

  // ---- PV + output, two 16-row sweeps ----
#pragma unroll
  for (int rt = 0; rt < 2; rt++) {
    if (rt == 1) {
#pragma unroll
      for (int ct = 0; ct < 16; ct++)
#pragma unroll
        for (int r = 0; r < 4; r++)
          Pw[(lq * 4 + r) * 264 + ct * 16 + lrow] = f2bf(acc2[1][ct][r] * inv[1][r]);
    }
    fx4 accO[5] = {};
#pragma unroll
    for (int kc = 0; kc < 8; kc++) {
      s16x8 a = *(const s16x8*)&Pw[lrow * 264 + kc * 32 + lq * 8];
#pragma unroll
      for (int tt = 0; tt < 5; tt++) {
        s16x8 b = *(const s16x8*)&Vt[(tt * 16 + lrow) * 264 + kc * 32 + lq * 8];
        accO[tt] = mfma16(a, b, accO[tt]);
      }
    }
    const int srow = s0 + w * 32 + rt * 16 + lq * 4;
#pragma unroll
    for (int tt = 0; tt < 5; tt++) {
      const int col = h * 80 + tt * 16 + lrow;
#pragma unroll
      for (int r = 0; r < 4; r++)
        Ob[(size_t)(srow + r) * DIM + col] = f2bf(accO[tt][r]);
    }
  }
}

// ---------------- proj GEMM: 256x256 tile, BK=32 quad-buffer ring ----------------
// NEW: ports mega's MEASURED GEMM structure (512 thr / 8 waves / 32 MFMA per step
// per wave / depth-3 counted vmcnt(8) ring) to the projection. Grid (32,5) = 160
// blocks; staged LDS traffic halves vs 128^2 (210 MB vs 419 MB); round-robin
// block->XCD keeps each M-panel's A resident in one XCD's L2 across all N (blocks
// M,N and M,N+1 are 32 apart = same XCD mod 8).
// Ledger: 128^2 dbuf proj ~125us (~214 TF) across rounds 0-4; 128^2 BK=32 ring
// regressed (142us, 16 MFMA/step too short) - tile size was the fix, not schedule.
// LDS 128 KB: Abuf 4x16K @0, Bbuf 4x16K @65536. 1 block/CU, 2 waves/SIMD.
__global__ __launch_bounds__(512, 2) void gemm_proj(const unsigned short* __restrict__ A,
                                                    const unsigned short* __restrict__ Bt,
                                                    const float* __restrict__ bias,
                                                    float* __restrict__ C) {
  __shared__ __attribute__((aligned(16))) char smem[131072];
  char* Abuf = smem;          // 4 x 16384
  char* Bbuf = smem + 65536;  // 4 x 16384

  const int t = threadIdx.x;
  const int lane = t & 63, w = t >> 6;
  const int lrow = lane & 15, lq = lane >> 4;
  const int wm = w >> 1, wn = w & 1;  // 4x2 wave grid, per-wave 64x128 output
  const int m0 = blockIdx.x * 256, n0 = blockIdx.y * 256;

  // staging geometry (BK=32): identical to mega. per matrix 1024 chunks/step;
  // thread covers rows tr2 and tr2+128; stored pos t&3 holds global chunk
  // (t&3)^((t>>3)&3)  (XOR swizzle -> ~2-way banks on ds_read_b128).
  const int tr2 = t >> 2;  // 0..127
  const int g8 = ((t & 3) ^ ((t >> 3) & 3)) * 8;
  const unsigned short* pA32[2];
  pA32[0] = A + (size_t)(m0 + tr2) * 1280 + g8;
  pA32[1] = pA32[0] + (size_t)128 * 1280;
  const unsigned short* pB32[2];
  pB32[0] = Bt + (size_t)(n0 + tr2) * 1280 + g8;
  pB32[1] = pB32[0] + (size_t)128 * 1280;

  const int swzr = (lq ^ ((lrow >> 1) & 3)) * 16;
  int offA32[4], offB32[8];
#pragma unroll
  for (int i = 0; i < 4; i++) offA32[i] = (wm * 64 + i * 16 + lrow) * 64 + swzr;
#pragma unroll
  for (int j = 0; j < 8; j++) offB32[j] = (wn * 128 + j * 16 + lrow) * 64 + swzr;

  fx4 acc[4][8] = {};

  auto STAGE = [&](int k) {
    const int kof = k * 32;
    char* da = Abuf + (k & 3) * 16384 + w * 1024;
    char* db = Bbuf + (k & 3) * 16384 + w * 1024;
    gload_lds16(pA32[0] + kof, da);
    gload_lds16(pB32[0] + kof, db);
    gload_lds16(pA32[1] + kof, da + 8192);
    gload_lds16(pB32[1] + kof, db + 8192);
  };
  auto COMP = [&](int k) {
    const char* As = Abuf + (k & 3) * 16384;
    const char* Bs = Bbuf + (k & 3) * 16384;
    s16x8 a[4], b[8];
#pragma unroll
    for (int i = 0; i < 4; i++) a[i] = *(const s16x8*)(As + offA32[i]);
#pragma unroll
    for (int j = 0; j < 8; j++) b[j] = *(const s16x8*)(Bs + offB32[j]);
    __builtin_amdgcn_s_setprio(1);
#pragma unroll
    for (int i = 0; i < 4; i++)
#pragma unroll
      for (int j = 0; j < 8; j++)
        acc[i][j] = mfma16(a[i], b[j], acc[i][j]);
    __builtin_amdgcn_s_setprio(0);
  };

  STAGE(0); STAGE(1); STAGE(2);
  for (int k = 0; k < 38; k++) {
    asm volatile("s_waitcnt vmcnt(8)\n\ts_barrier" ::: "memory");
    if (k < 37) STAGE(k + 3);
    COMP(k);
  }
  asm volatile("s_waitcnt vmcnt(4)\n\ts_barrier" ::: "memory");
  COMP(38);
  asm volatile("s_waitcnt vmcnt(0)\n\ts_barrier" ::: "memory");
  COMP(39);

  // epilogue: acc + bias -> C (f32)
#pragma unroll
  for (int i = 0; i < 4; i++) {
    const int row_base = m0 + wm * 64 + i * 16 + lq * 4;
#pragma unroll
    for (int j = 0; j < 8; j++) {
      const int col = n0 + wn * 128 + j * 16 + lrow;
      const float bv = bias[col];
#pragma unroll
      for (int r = 0; r < 4; r++)
        C[(size_t)(row_base + r) * DIM + col] = acc[i][j][r] + bv;
    }
  }
}

// ---------------- launch ----------------
extern "C" void kernel_launch(void* const* d_in, const int* in_sizes, int n_in,
                              void* d_out, int out_size, void* d_ws, size_t ws_size,
                              hipStream_t stream) {
  const float* hidden = (const float*)d_in[0];
  // d_in[1] = cu_seqlens: fixed layout (32 chunks of 256), unused
  const float* cosb = (const float*)d_in[2];
  const float* sinb = (const float*)d_in[3];
  const float* w_qkv = (const float*)d_in[4];
  const float* b_qkv = (const float*)d_in[5];
  const float* w_proj = (const float*)d_in[6];
  const float* b_proj = (const float*)d_in[7];
  float* out = (float*)d_out;

  // workspace layout (bytes)
  char* ws = (char*)d_ws;
  constexpr size_t HB_B = (size_t)SEQ * DIM * 2;    // 20,971,520 hidden bf16
  constexpr size_t WQT_B = (size_t)NQKV * DIM * 2;  //  9,830,400 w_qkv^T bf16
  constexpr size_t WPT_B = (size_t)DIM * DIM * 2;   //  3,276,800 w_proj^T bf16
  constexpr size_t OB_B = (size_t)SEQ * DIM * 2;    // 20,971,520 attn out bf16
  size_t off = 0;
  unsigned short* hb = (unsigned short*)(ws + off);     off += HB_B;
  unsigned short* wqkvT = (unsigned short*)(ws + off);  off += WQT_B;
  unsigned short* wprojT = (unsigned short*)(ws + off); off += WPT_B;
  unsigned short* Ob = (unsigned short*)(ws + off);     off += OB_B;
  if (ws_size < off) return;

  // 1. cast hidden to bf16
  cast_bf16_kernel<<<dim3((SEQ * DIM / 4 + 255) / 256), dim3(256), 0, stream>>>(
      hidden, hb, SEQ * DIM / 4);
  // 2. transpose-cast weights
  transpose_cast_kernel<<<dim3(NQKV / 32, DIM / 32), dim3(256), 0, stream>>>(
      w_qkv, wqkvT, DIM, NQKV);
  transpose_cast_kernel<<<dim3(DIM / 32, DIM / 32), dim3(256), 0, stream>>>(
      w_proj, wprojT, DIM, DIM);
  // 3. mega: QKV GEMM + RoPE + attention -> Ob
  mega_attn<<<dim3(NIMG, HEADS), dim3(512), 0, stream>>>(hb, wqkvT, b_qkv, cosb, sinb, Ob);
  // 4. proj GEMM (+bias) -> d_out (f32), 256x256 tiles
  gemm_proj<<<dim3(SEQ / 256, DIM / 256), dim3(512), 0, stream>>>(
      Ob, wprojT, b_proj, out);
}

// Round 6
// 275.299 us; speedup vs baseline: 1.0431x; 1.0089x over previous
//
#include <hip/hip_runtime.h>
#include <stdint.h>

#define DEVFN __device__ __forceinline__

typedef short s16x8 __attribute__((ext_vector_type(8)));
typedef __bf16 bf16x8 __attribute__((ext_vector_type(8)));
typedef float fx4 __attribute__((ext_vector_type(4)));

// Problem constants (fixed by the reference)
constexpr int SEQ = 8192, DIM = 1280, HEADS = 16;
constexpr int NIMG = 32;
constexpr int NQKV = 3840;  // 3*DIM
constexpr int TS = 84;      // raw Q/K tile stride (168B rows: scatter = 2 lanes/bank, free)

DEVFN unsigned short f2bf(float f) {
  union { float f; unsigned u; } v; v.f = f;
  unsigned r = v.u + 0x7FFFu + ((v.u >> 16) & 1u);  // RNE
  return (unsigned short)(r >> 16);
}
DEVFN float bf2f(unsigned short u) {
  union { unsigned u; float f; } v; v.u = ((unsigned)u) << 16;
  return v.f;
}

DEVFN fx4 mfma16(s16x8 a, s16x8 b, fx4 c) {
  return __builtin_amdgcn_mfma_f32_16x16x32_bf16(
      __builtin_bit_cast(bf16x8, a), __builtin_bit_cast(bf16x8, b), c, 0, 0, 0);
}

DEVFN void gload_lds16(const void* g, void* l) {
  // global -> LDS direct, 16B per lane; LDS dest = wave-uniform base + lane*16
  __builtin_amdgcn_global_load_lds(
      (__attribute__((address_space(1))) void*)(uintptr_t)g,
      (__attribute__((address_space(3))) void*)l, 16, 0, 0);
}

// ---------------- fused prep: cast hidden + transpose-cast both weights ----------------
// Block-range routing: [0,10240) cast (4 f32->bf16 per thread); [10240,15040)
// w_qkv transpose (120x40 tiles); [15040,16640) w_proj transpose (40x40 tiles).
// Saves 2 kernel launches vs separate dispatches.
__global__ __launch_bounds__(256) void prep_kernel(const float* __restrict__ hidden,
                                                   unsigned short* __restrict__ hb,
                                                   const float* __restrict__ w_qkv,
                                                   unsigned short* __restrict__ wqkvT,
                                                   const float* __restrict__ w_proj,
                                                   unsigned short* __restrict__ wprojT) {
  const int b = blockIdx.x;
  if (b < 10240) {  // cast: 10240*256*4 = SEQ*DIM exactly
    const int i = b * 256 + threadIdx.x;
    float4 v = ((const float4*)hidden)[i];
    ushort4 o;
    o.x = f2bf(v.x); o.y = f2bf(v.y); o.z = f2bf(v.z); o.w = f2bf(v.w);
    ((ushort4*)hb)[i] = o;
    return;
  }
  __shared__ float tile[32][33];
  const float* W; unsigned short* T;
  int K, N, bx, by;
  if (b < 15040) {
    const int bb = b - 10240;
    bx = bb % 120; by = bb / 120; W = w_qkv; T = wqkvT; K = DIM; N = NQKV;
  } else {
    const int bb = b - 15040;
    bx = bb % 40; by = bb / 40; W = w_proj; T = wprojT; K = DIM; N = DIM;
  }
  const int tx = threadIdx.x & 31, ty = threadIdx.x >> 5;  // 32x8
  const int n0 = bx * 32, k0 = by * 32;
#pragma unroll
  for (int i = 0; i < 4; i++) {
    int r = ty + i * 8;
    tile[r][tx] = W[(size_t)(k0 + r) * N + n0 + tx];
  }
  __syncthreads();
#pragma unroll
  for (int i = 0; i < 4; i++) {
    int r = ty + i * 8;
    T[(size_t)(n0 + r) * K + k0 + tx] = f2bf(tile[tx][r]);
  }
}

// ---------------- mega kernel: QKV GEMM + bias + RoPE + attention ----------------
// FROZEN (measured 131-134us across R3/R4/R5, MfmaUtil ~31.8). Block = (img n,
// head h), 512 threads = 8 waves (4x2). GEMM: 256x256x1280, BK=32 quad-buffer ring
// (4 x 16KB per matrix), depth-3 prefetch, counted s_waitcnt vmcnt(8) (T3/T4),
// s_setprio around MFMA (T5). Epilogue scatters acc+bias branchlessly into raw Q/K
// (stride 84) and V directly transposed into Vt[80][264]; then rope+QK^T+softmax+PV.
// LDS (153600 B): ring Abuf 4x16K @0, Bbuf 4x16K @65536 (dead after K-loop);
// X@0 (rawK84 -> Ks[256][104] -> P-scratch 8x16x264), Y@67584 (rawQ84),
// Vt@110592 (80x264).
__global__ __launch_bounds__(512, 2) void mega_attn(const unsigned short* __restrict__ hb,
                                                    const unsigned short* __restrict__ wqkvT,
                                                    const float* __restrict__ b_qkv,
                                                    const float* __restrict__ cosb,
                                                    const float* __restrict__ sinb,
                                                    unsigned short* __restrict__ Ob) {
  __shared__ __attribute__((aligned(16))) char smem[153600];
  unsigned short* X = (unsigned short*)smem;
  unsigned short* Y = (unsigned short*)(smem + 67584);
  unsigned short* Vt = (unsigned short*)(smem + 110592);  // [80][264]
  char* Abuf = smem;          // 4 x 16384
  char* Bbuf = smem + 65536;  // 4 x 16384

  const int t = threadIdx.x;
  const int lane = t & 63, w = t >> 6;
  const int lrow = lane & 15, lq = lane >> 4;
  const int n = blockIdx.x, h = blockIdx.y;
  const int s0 = n * 256;
  const int wm = w >> 1, wn = w & 1;

  // staging geometry (BK=32): per matrix 1024 16B-chunks/step (256 rows x 4 chunks);
  // thread covers slots t and t+512. slot s -> row r = s>>2, pos p = s&3; stored pos p
  // holds global chunk p ^ ((r>>1)&3)  (swizzle -> ~2-way banks on ds_read_b128).
  const int tr2 = t >> 2;  // 0..127
  const int g8 = ((t & 3) ^ ((t >> 3) & 3)) * 8;
  const unsigned short* pA32[2];
  pA32[0] = hb + (size_t)(s0 + tr2) * 1280 + g8;
  pA32[1] = pA32[0] + (size_t)128 * 1280;
  const unsigned short* pB32[2];
#pragma unroll
  for (int i = 0; i < 2; i++) {
    const int r = tr2 + i * 128;
    const int rr = r < 240 ? r : 239;  // pad rows clamp (cols 240..255 never used)
    const int sgm = (rr >= 160) ? 2 : (rr >= 80 ? 1 : 0);
    pB32[i] = wqkvT + (size_t)(sgm * DIM + h * 80 + (rr - sgm * 80)) * 1280 + g8;
  }

  // fragment read offsets: row ra, chunk lq ^ ((ra>>1)&3); (ra>>1)&3 == (lrow>>1)&3.
  const int swzr = (lq ^ ((lrow >> 1) & 3)) * 16;
  int offA32[4], offB32[8];
#pragma unroll
  for (int i = 0; i < 4; i++) offA32[i] = (wm * 64 + i * 16 + lrow) * 64 + swzr;
#pragma unroll
  for (int j = 0; j < 8; j++) offB32[j] = (wn * 128 + j * 16 + lrow) * 64 + swzr;

  fx4 acc[4][8] = {};

  auto STAGE = [&](int k) {
    const int kof = k * 32;
    char* da = Abuf + (k & 3) * 16384 + w * 1024;
    char* db = Bbuf + (k & 3) * 16384 + w * 1024;
    gload_lds16(pA32[0] + kof, da);
    gload_lds16(pB32[0] + kof, db);
    gload_lds16(pA32[1] + kof, da + 8192);
    gload_lds16(pB32[1] + kof, db + 8192);
  };
  auto COMP = [&](int k) {
    const char* As = Abuf + (k & 3) * 16384;
    const char* Bs = Bbuf + (k & 3) * 16384;
    s16x8 a[4], b[8];
#pragma unroll
    for (int i = 0; i < 4; i++) a[i] = *(const s16x8*)(As + offA32[i]);
#pragma unroll
    for (int j = 0; j < 8; j++) b[j] = *(const s16x8*)(Bs + offB32[j]);
    __builtin_amdgcn_s_setprio(1);
#pragma unroll
    for (int i = 0; i < 4; i++)
#pragma unroll
      for (int j = 0; j < 8; j++)
        acc[i][j] = mfma16(a[i], b[j], acc[i][j]);
    __builtin_amdgcn_s_setprio(0);
  };

  // prologue: 3 K-steps in flight (12 loads/thread)
  STAGE(0); STAGE(1); STAGE(2);
  // main loop: wait own oldest 4 loads (buf k) -> after barrier everyone's buf[k]
  // is complete; bufs k+1,k+2 stay in flight ACROSS the barrier (counted vmcnt).
  for (int k = 0; k < 38; k++) {
    asm volatile("s_waitcnt vmcnt(8)\n\ts_barrier" ::: "memory");
    if (k < 37) STAGE(k + 3);
    COMP(k);
  }
  asm volatile("s_waitcnt vmcnt(4)\n\ts_barrier" ::: "memory");
  COMP(38);
  asm volatile("s_waitcnt vmcnt(0)\n\ts_barrier" ::: "memory");
  COMP(39);
  __syncthreads();  // all fragment reads done before staging regions become Q/K/Vt

  // ---- epilogue scatter (branchless stride-select): acc + bias ->
  //      sgm 0/1: raw Q (Y) / K (X), addr = row*84 + d
  //      sgm 2:   Vt transposed,      addr = d*264 + row
#pragma unroll
  for (int j = 0; j < 8; j++) {
    const int col = wn * 128 + j * 16 + lrow;
    if (col < 240) {
      const int sgm = (col >= 160) ? 2 : (col >= 80 ? 1 : 0);
      const int d = col - sgm * 80;
      const float bv = b_qkv[sgm * DIM + h * 80 + d];
      unsigned short* dst = (sgm == 0) ? Y : (sgm == 1) ? X : Vt;
      const int rs = (sgm == 2) ? 1 : TS;
      const int dd = (sgm == 2) ? 264 : 1;
      const int dbase = d * dd;
#pragma unroll
      for (int i = 0; i < 4; i++) {
        const int row = wm * 64 + i * 16 + lq * 4;
#pragma unroll
        for (int r = 0; r < 4; r++)
          dst[(row + r) * rs + dbase] = f2bf(acc[i][j][r] + bv);
      }
    }
  }
  __syncthreads();  // B1: raw Q/K + Vt complete

  // ---- K rope -> regs; Q rope -> A-fragments (wave w owns q-rows w*32..w*32+31) ----
  unsigned short kout[5][8];
  int kro[5], kco[5];
#pragma unroll
  for (int i = 0; i < 5; i++) {
    const int idx = t + i * 512;
    const unsigned r = (unsigned)idx / 10u, c = (unsigned)idx % 10u;
    kro[i] = r; kco[i] = c;
    s16x8 xv = *(const s16x8*)&X[r * TS + c * 8];
    const unsigned cp = (c < 5) ? c + 5 : c - 5;  // partner chunk (+-40 elems)
    s16x8 pv = *(const s16x8*)&X[r * TS + cp * 8];
    const float sgn = (c < 5) ? -1.f : 1.f;
    const float* cf = cosb + (size_t)(s0 + r) * 80 + c * 8;
    const float* sf = sinb + (size_t)(s0 + r) * 80 + c * 8;
#pragma unroll
    for (int j = 0; j < 8; j++)
      kout[i][j] = f2bf(bf2f((unsigned short)xv[j]) * cf[j] +
                        sgn * bf2f((unsigned short)pv[j]) * sf[j]);
  }

  s16x8 aq[2][3];
#pragma unroll
  for (int rt = 0; rt < 2; rt++) {
#pragma unroll
    for (int c = 0; c < 3; c++) {
      const int row = w * 32 + rt * 16 + lrow;
      const int d0 = c * 32 + lq * 8;
      s16x8 fr = {};
      if (d0 < 80) {
        s16x8 xv = *(const s16x8*)&Y[row * TS + d0];
        const int dp = (d0 < 40) ? d0 + 40 : d0 - 40;
        s16x8 pv = *(const s16x8*)&Y[row * TS + dp];
        const float sgn = (d0 < 40) ? -1.f : 1.f;
        const float* cf = cosb + (size_t)(s0 + row) * 80 + d0;
        const float* sf = sinb + (size_t)(s0 + row) * 80 + d0;
#pragma unroll
        for (int j = 0; j < 8; j++)
          fr[j] = (short)f2bf(bf2f((unsigned short)xv[j]) * cf[j] +
                              sgn * bf2f((unsigned short)pv[j]) * sf[j]);
      }
      aq[rt][c] = fr;
    }
  }
  __syncthreads();  // B2: rawK/rawQ reads done

  // ---- write rope'd K at stride 104 (2-way bank aliasing = free) + zero pad ----
#pragma unroll
  for (int i = 0; i < 5; i++)
    *(int4*)&X[kro[i] * 104 + kco[i] * 8] = *(const int4*)kout[i];
  {
    const int r = t >> 1, wh = t & 1;
    const int4 z = {0, 0, 0, 0};
    *(int4*)&X[r * 104 + 80 + wh * 8] = z;
  }
  __syncthreads();  // B3

  // ---- QK^T: 2 row-tiles x 16 col-tiles, K = 96 ----
  fx4 acc2[2][16] = {};
#pragma unroll
  for (int c = 0; c < 3; c++) {
#pragma unroll
    for (int ct = 0; ct < 16; ct++) {
      s16x8 b = *(const s16x8*)&X[(ct * 16 + lrow) * 104 + c * 32 + lq * 8];
      acc2[0][ct] = mfma16(aq[0][c], b, acc2[0][ct]);
      acc2[1][ct] = mfma16(aq[1][c], b, acc2[1][ct]);
    }
  }

  // ---- softmax (rows wave-local: row = rt*16 + lq*4 + r) ----
  const float kscale = 0.11180339887498949f * 1.4426950408889634f;  // 80^-0.5 * log2e
  float inv[2][4];
#pragma unroll
  for (int rt = 0; rt < 2; rt++) {
    float mx[4] = {-1e30f, -1e30f, -1e30f, -1e30f};
#pragma unroll
    for (int ct = 0; ct < 16; ct++)
#pragma unroll
      for (int r = 0; r < 4; r++) mx[r] = fmaxf(mx[r], acc2[rt][ct][r]);
#pragma unroll
    for (int r = 0; r < 4; r++) {
      mx[r] = fmaxf(mx[r], __shfl_xor(mx[r], 1));
      mx[r] = fmaxf(mx[r], __shfl_xor(mx[r], 2));
      mx[r] = fmaxf(mx[r], __shfl_xor(mx[r], 4));
      mx[r] = fmaxf(mx[r], __shfl_xor(mx[r], 8));
    }
    float sm[4] = {0.f, 0.f, 0.f, 0.f};
#pragma unroll
    for (int ct = 0; ct < 16; ct++)
#pragma unroll
      for (int r = 0; r < 4; r++) {
        float e = exp2f((acc2[rt][ct][r] - mx[r]) * kscale);
        acc2[rt][ct][r] = e;
        sm[r] += e;
      }
#pragma unroll
    for (int r = 0; r < 4; r++) {
      sm[r] += __shfl_xor(sm[r], 1);
      sm[r] += __shfl_xor(sm[r], 2);
      sm[r] += __shfl_xor(sm[r], 4);
      sm[r] += __shfl_xor(sm[r], 8);
      inv[rt][r] = 1.f / sm[r];
    }
  }
  __syncthreads();  // B4: Ks dead; X becomes per-wave P-scratch

  // ---- P (rt=0) to per-wave scratch (wave-private; Vt complete since B1) ----
  unsigned short* Pw = X + w * 4224;  // 16 rows x 264 elems
#pragma unroll
  for (int ct = 0; ct < 16; ct++)
#pragma unroll
    for (int r = 0; r < 4; r++)
      Pw[(lq * 4 + r) * 264 + ct * 16 + lrow] = f2bf(acc2[0][ct][r] * inv[0][r]);

  // ---- PV + output, two 16-row sweeps ----
#pragma unroll
  for (int rt = 0; rt < 2; rt++) {
    if (rt == 1) {
#pragma unroll
      for (int ct = 0; ct < 16; ct++)
#pragma unroll
        for (int r = 0; r < 4; r++)
          Pw[(lq * 4 + r) * 264 + ct * 16 + lrow] = f2bf(acc2[1][ct][r] * inv[1][r]);
    }
    fx4 accO[5] = {};
#pragma unroll
    for (int kc = 0; kc < 8; kc++) {
      s16x8 a = *(const s16x8*)&Pw[lrow * 264 + kc * 32 + lq * 8];
#pragma unroll
      for (int tt = 0; tt < 5; tt++) {
        s16x8 b = *(const s16x8*)&Vt[(tt * 16 + lrow) * 264 + kc * 32 + lq * 8];
        accO[tt] = mfma16(a, b, accO[tt]);
      }
    }
    const int srow = s0 + w * 32 + rt * 16 + lq * 4;
#pragma unroll
    for (int tt = 0; tt < 5; tt++) {
      const int col = h * 80 + tt * 16 + lrow;
#pragma unroll
      for (int r = 0; r < 4; r++)
        Ob[(size_t)(srow + r) * DIM + col] = f2bf(accO[tt][r]);
    }
  }
}

// ---------------- proj GEMM: 128x320 tile, BK=64 dbuf, grid 256 = 1 block/CU ----------------
// NEW: exact-CU-coverage tiling (grid 64x4 = 256 blocks, no idle CUs, no tail;
// the 256^2 version left 96/256 CUs idle). Proven vmcnt(0) dbuf schedule (ring at
// short phases is a measured regression, R3); 8 waves (2M x 4N), per-wave 64x80
// output -> 40 MFMA per K-step (mega-like phase length). XOR-8 swizzle staging.
// LDS 112 KB: As 2x16K @0, Bs 2x40K @32768. A panels XCD-local (same-m blocks are
// 64 apart = 0 mod 8); B (3.3 MB) is L3-resident.
__global__ __launch_bounds__(512, 2) void gemm_proj(const unsigned short* __restrict__ A,
                                                    const unsigned short* __restrict__ Bt,
                                                    const float* __restrict__ bias,
                                                    float* __restrict__ C) {
  __shared__ __attribute__((aligned(16))) char smem[114688];
  char* Abuf = smem;          // 2 x 16384
  char* Bbuf = smem + 32768;  // 2 x 40960

  const int t = threadIdx.x;
  const int lane = t & 63, w = t >> 6;
  const int lrow = lane & 15, lq = lane >> 4;
  const int l7 = lrow & 7;
  const int wm = w >> 2, wn = w & 3;  // 2x4 wave grid, per-wave 64x80 output
  const int m0 = blockIdx.x * 128, n0 = blockIdx.y * 320;

  // staging (BK=64, 128B rows = 8 chunks): A 1024 chunks/step (thread: c=t, t+512),
  // B 2560 chunks/step (c = t + i*512, i=0..4). chunk c -> row c>>3, pos c&7; stored
  // pos t&7 holds global chunk (t&7)^(row&7) (XOR-8 -> conflict-free ds_read_b128).
  const int tr3 = t >> 3;  // 0..63
  const int cch = ((t & 7) ^ (tr3 & 7)) * 8;
  const unsigned short* pA = A + (size_t)(m0 + tr3) * 1280 + cch;   // rows tr3, tr3+64
  const unsigned short* pB = Bt + (size_t)(n0 + tr3) * 1280 + cch;  // rows tr3 + i*64

  int offA[4][2], offB[5][2];
#pragma unroll
  for (int i = 0; i < 4; i++) {
    const int ra = wm * 64 + i * 16 + lrow;  // ra & 7 == l7
    offA[i][0] = ra * 128 + (lq ^ l7) * 16;
    offA[i][1] = ra * 128 + ((lq + 4) ^ l7) * 16;
  }
#pragma unroll
  for (int j = 0; j < 5; j++) {
    const int rb = wn * 80 + j * 16 + lrow;  // 80 % 8 == 0 -> rb & 7 == l7
    offB[j][0] = rb * 128 + (lq ^ l7) * 16;
    offB[j][1] = rb * 128 + ((lq + 4) ^ l7) * 16;
  }

  fx4 acc[4][5] = {};

  auto STAGE = [&](int k, int buf) {
    const int kof = k * 64;
    char* da = Abuf + buf * 16384 + w * 1024;
    char* db = Bbuf + buf * 40960 + w * 1024;
    gload_lds16(pA + kof, da);
    gload_lds16(pA + (size_t)64 * 1280 + kof, da + 8192);
#pragma unroll
    for (int i = 0; i < 5; i++)
      gload_lds16(pB + (size_t)i * 64 * 1280 + kof, db + i * 8192);
  };

  STAGE(0, 0);
  for (int k = 0; k < 20; k++) {
    asm volatile("s_waitcnt vmcnt(0)\n\ts_barrier" ::: "memory");
    if (k < 19) STAGE(k + 1, (k + 1) & 1);  // flies during compute(k)
    const char* As = Abuf + (k & 1) * 16384;
    const char* Bs = Bbuf + (k & 1) * 40960;
#pragma unroll
    for (int kq = 0; kq < 2; kq++) {
      s16x8 a[4], b[5];
#pragma unroll
      for (int i = 0; i < 4; i++) a[i] = *(const s16x8*)(As + offA[i][kq]);
#pragma unroll
      for (int j = 0; j < 5; j++) b[j] = *(const s16x8*)(Bs + offB[j][kq]);
      __builtin_amdgcn_s_setprio(1);
#pragma unroll
      for (int i = 0; i < 4; i++)
#pragma unroll
        for (int j = 0; j < 5; j++)
          acc[i][j] = mfma16(a[i], b[j], acc[i][j]);
      __builtin_amdgcn_s_setprio(0);
    }
  }

  // epilogue: acc + bias -> C (f32)
#pragma unroll
  for (int i = 0; i < 4; i++) {
    const int row_base = m0 + wm * 64 + i * 16 + lq * 4;
#pragma unroll
    for (int j = 0; j < 5; j++) {
      const int col = n0 + wn * 80 + j * 16 + lrow;
      const float bv = bias[col];
#pragma unroll
      for (int r = 0; r < 4; r++)
        C[(size_t)(row_base + r) * DIM + col] = acc[i][j][r] + bv;
    }
  }
}

// ---------------- launch ----------------
extern "C" void kernel_launch(void* const* d_in, const int* in_sizes, int n_in,
                              void* d_out, int out_size, void* d_ws, size_t ws_size,
                              hipStream_t stream) {
  const float* hidden = (const float*)d_in[0];
  // d_in[1] = cu_seqlens: fixed layout (32 chunks of 256), unused
  const float* cosb = (const float*)d_in[2];
  const float* sinb = (const float*)d_in[3];
  const float* w_qkv = (const float*)d_in[4];
  const float* b_qkv = (const float*)d_in[5];
  const float* w_proj = (const float*)d_in[6];
  const float* b_proj = (const float*)d_in[7];
  float* out = (float*)d_out;

  // workspace layout (bytes)
  char* ws = (char*)d_ws;
  constexpr size_t HB_B = (size_t)SEQ * DIM * 2;    // 20,971,520 hidden bf16
  constexpr size_t WQT_B = (size_t)NQKV * DIM * 2;  //  9,830,400 w_qkv^T bf16
  constexpr size_t WPT_B = (size_t)DIM * DIM * 2;   //  3,276,800 w_proj^T bf16
  constexpr size_t OB_B = (size_t)SEQ * DIM * 2;    // 20,971,520 attn out bf16
  size_t off = 0;
  unsigned short* hb = (unsigned short*)(ws + off);     off += HB_B;
  unsigned short* wqkvT = (unsigned short*)(ws + off);  off += WQT_B;
  unsigned short* wprojT = (unsigned short*)(ws + off); off += WPT_B;
  unsigned short* Ob = (unsigned short*)(ws + off);     off += OB_B;
  if (ws_size < off) return;

  // 1. fused prep: cast hidden + transpose-cast w_qkv/w_proj (one launch)
  prep_kernel<<<dim3(16640), dim3(256), 0, stream>>>(hidden, hb, w_qkv, wqkvT,
                                                     w_proj, wprojT);
  // 2. mega: QKV GEMM + RoPE + attention -> Ob
  mega_attn<<<dim3(NIMG, HEADS), dim3(512), 0, stream>>>(hb, wqkvT, b_qkv, cosb, sinb, Ob);
  // 3. proj GEMM (+bias) -> d_out (f32), 128x320 tiles, grid 256 = exact CU coverage
  gemm_proj<<<dim3(SEQ / 128, DIM / 320), dim3(512), 0, stream>>>(
      Ob, wprojT, b_proj, out);
}